// Round 16
// baseline (531.836 us; speedup 1.0000x reference)
//
#include <hip/hip_runtime.h>

typedef unsigned short u16;
typedef unsigned int u32;
typedef unsigned long long u64;
typedef __attribute__((ext_vector_type(8))) short short8;
typedef __attribute__((ext_vector_type(4))) float f32x4;
typedef __attribute__((ext_vector_type(16))) float f32x16;
typedef __attribute__((ext_vector_type(2))) unsigned int u32x2;

#define NPTS 1048576
#define TILES 128
#define NBLK (NPTS / (32 * TILES))   // 256 blocks = 1 per CU
#define HPE 72    // 64-col row stride (144 B)
#define HPB 264   // 256-col row stride (528 B)
#define HPF 136   // 128-col row stride (272 B)

__device__ __forceinline__ u16 f2b(float f) {
    return (u16)((__float_as_uint(f) + 0x8000u) >> 16);
}
// NOTE (R15 lesson): v_cvt_pk_bf16_f32 TRUNCATES (RTZ) — systematic bias
// accumulates through the 5-layer chain and fails the RNE-calibrated threshold
// (absmax 6.6e-2 > 1.08e-2). Keep round-half-up f2b + perm packing.
__device__ __forceinline__ u32 pk(float a, float b) {
    return (u32)f2b(a) | ((u32)f2b(b) << 16);
}
#define INV2PI 0.15915494309189535f
__device__ __forceinline__ float sinrev(float t) {
    t = t - floorf(t);
    return __builtin_amdgcn_sinf(t);
}

// Barrier with LDS-only drain (R10-verified +15us): __syncthreads() would drain
// vmcnt(0) (global loads + store acks) at every phase; only LDS visibility needed.
__device__ __forceinline__ void bar_lds() {
    asm volatile("s_waitcnt lgkmcnt(0)\n\ts_barrier" ::: "memory");
}

// ---------------- weight convert(fp32->bf16) + transpose/pad prepass ----------------
// ws layout (bf16), WT[n][k] row-major in k. Encoding columns are PERMUTED so enc
// threads write contiguous spans (vector ds_write) — weight rows remapped to match.
// sE cols: k<60: d=k/6, ph=(k%6)/3, c=k%3 -> W1 row (ph?33:3)+3d+c ; 60..62: raw x ;
//          63: b1 fold.
// sG cols: 0..14 feat ; 15 zero ; 16..39: j=k-16, d=j/6, ph=(j%6)/3, c=j%3 ->
//          Wc1 row (ph?30:18)+3d+c ; 40..42: dn (Wc1 rows 15..17) ; 43: bc1 fold ;
//          44..63 zero.
//  WT1  @      0 : 256 x  64
//  WT2  @  16384 : 256 x 256
//  WT3  @  81920 : 256 x 256
//  WT4  @ 147456 :  16 x 256
//  WTc1 @ 151552 : 128 x  64
//  WTc2 @ 159744 :  16 x 128   (Wc2 128x3, n>=3 -> 0)
__global__ void prep_weights(const float* __restrict__ W1, const float* __restrict__ b1,
                             const float* __restrict__ W2,
                             const float* __restrict__ W3, const float* __restrict__ W4,
                             const float* __restrict__ Wc1, const float* __restrict__ bc1,
                             const float* __restrict__ Wc2,
                             u16* __restrict__ ws) {
    int i = blockIdx.x * 256 + threadIdx.x;
    if (i < 16384) {
        int n = i >> 6, k = i & 63;
        u16 v;
        if (k < 60) {
            int d = k / 6, rem = k % 6, ph = rem / 3, c = rem % 3;
            v = f2b(W1[((ph ? 33 : 3) + 3 * d + c) * 256 + n]);
        } else if (k < 63) v = f2b(W1[(k - 60) * 256 + n]);
        else v = f2b(b1[n]);
        ws[i] = v; return;
    }
    i -= 16384;
    if (i < 65536) { int n = i >> 8, k = i & 255; ws[16384 + i]  = f2b(W2[k * 256 + n]); return; }
    i -= 65536;
    if (i < 65536) { int n = i >> 8, k = i & 255; ws[81920 + i]  = f2b(W3[k * 256 + n]); return; }
    i -= 65536;
    if (i < 4096)  { int n = i >> 8, k = i & 255; ws[147456 + i] = f2b(W4[k * 16 + n]); return; }
    i -= 4096;
    if (i < 8192) {
        int n = i >> 6, k = i & 63;
        u16 v;
        if (k < 15)       v = f2b(Wc1[k * 128 + n]);
        else if (k == 15) v = 0;
        else if (k < 40) {
            int j = k - 16, d = j / 6, rem = j % 6, ph = rem / 3, c = rem % 3;
            v = f2b(Wc1[((ph ? 30 : 18) + 3 * d + c) * 128 + n]);
        } else if (k < 43) v = f2b(Wc1[(15 + k - 40) * 128 + n]);
        else if (k == 43) v = f2b(bc1[n]);
        else v = 0;
        ws[151552 + i] = v; return;
    }
    i -= 8192;
    if (i < 2048)  { int n = i >> 7, k = i & 127; ws[159744 + i] = (n < 3) ? f2b(Wc2[k * 3 + n]) : (u16)0; return; }
}

// Epilogue for 32x32x16 (A=weights, B=acts): lane = batch row, regs = 16 neurons.
template <bool BIAS>
__device__ __forceinline__ void epi32(const f32x16& acc, u16* rowp, const float* bias,
                                      int nbase, int kh) {
#pragma unroll
    for (int g = 0; g < 4; ++g) {
        const int mq = nbase + 8 * g + 4 * kh;
        float v[4];
#pragma unroll
        for (int j = 0; j < 4; ++j) v[j] = acc[4 * g + j];
        if (BIAS) {
            const f32x4 bi = *(const f32x4*)(bias + mq);
#pragma unroll
            for (int j = 0; j < 4; ++j) v[j] += bi[j];
        }
#pragma unroll
        for (int j = 0; j < 4; ++j) v[j] = fmaxf(v[j], 0.f);
        unsigned int u[4];
#pragma unroll
        for (int j = 0; j < 4; ++j) u[j] = __float_as_uint(v[j]) + 0x8000u;
        u32x2 d;
        d.x = __builtin_amdgcn_perm(u[1], u[0], 0x07060302);
        d.y = __builtin_amdgcn_perm(u[3], u[2], 0x07060302);
        *(u32x2*)(rowp + mq) = d;
    }
}

template <int NKT, bool BIAS>
__device__ __forceinline__ void layer32(const short8* wr, const u16* src, int ss,
                                        u16* dst, int ds, const float* bias,
                                        int nbase, int ln, int kh) {
    f32x16 acc;
#pragma unroll
    for (int r = 0; r < 16; ++r) acc[r] = 0.f;
#pragma unroll
    for (int kt = 0; kt < NKT; ++kt) {
        const short8 bA = *(const short8*)(src + ln * ss + kt * 16 + kh * 8);
        acc = __builtin_amdgcn_mfma_f32_32x32x16_bf16(wr[kt], bA, acc, 0, 0, 0);
    }
    epi32<BIAS>(acc, dst + ln * ds, bias, nbase, kh);
}

// ---- encode split into preload (global loads, issued early) + compute ----
// j in [0,512): j<256 -> pos-encode job, else dir-encode job.
// Column order interleaved per-degree so each thread's outputs are CONTIGUOUS:
// pos thread g<5 writes cols 12g..12g+11 as 3x ds_write_b64 (byte 24g, 8-aligned);
// dir thread g<4 writes cols 16+6g..+5 as 3x ds_write_b32. Constant cols
// (sE 63; sG 15,43..63) prologue-initialized once.
__device__ __forceinline__ void enc_preload(const float* __restrict__ pos,
                                            const float* __restrict__ dir,
                                            long rb, int j, float* v) {
    if (j < 256) {
        const long row = rb + (j >> 3);
        v[0] = pos[row * 3 + 0]; v[1] = pos[row * 3 + 1]; v[2] = pos[row * 3 + 2];
    } else {
        const long row = rb + ((j - 256) >> 3);
        v[0] = dir[row * 3 + 0]; v[1] = dir[row * 3 + 1]; v[2] = dir[row * 3 + 2];
    }
}

__device__ __forceinline__ void enc_compute(const float* v, int j, u16* sEj, u16* sGj) {
    if (j < 256) {
        const int r = j >> 3, g = j & 7;
        float xn[3];
#pragma unroll
        for (int c = 0; c < 3; ++c) xn[c] = v[c] * (1.0f / 1.5f);
        u16* er = sEj + r * HPE;
        if (g < 5) {
            u32 wv[6];
#pragma unroll
            for (int dd = 0; dd < 2; ++dd) {
                const int d = 2 * g + dd;
                const float sc = (float)(1 << d);
                float p0[3], p1[3];
#pragma unroll
                for (int c = 0; c < 3; ++c) {
                    const float tv = xn[c] * sc * INV2PI;
                    p0[c] = sinrev(tv);
                    p1[c] = sinrev(tv + 0.25f);
                }
                wv[3 * dd + 0] = pk(p0[0], p0[1]);   // cols 6d+0, 6d+1
                wv[3 * dd + 1] = pk(p0[2], p1[0]);   // cols 6d+2, 6d+3
                wv[3 * dd + 2] = pk(p1[1], p1[2]);   // cols 6d+4, 6d+5
            }
            u64* dst = (u64*)(er + 12 * g);          // byte 24g, 8-aligned
            dst[0] = (u64)wv[0] | ((u64)wv[1] << 32);
            dst[1] = (u64)wv[2] | ((u64)wv[3] << 32);
            dst[2] = (u64)wv[4] | ((u64)wv[5] << 32);
        } else if (g == 5) {
            *(u32*)(er + 60) = pk(xn[0], xn[1]);
            er[62] = f2b(xn[2]);
            // er[63] const: prologue-initialized
        }
    } else {
        const int j2 = j - 256;
        const int r = j2 >> 3, g = j2 & 7;
        u16* gr = sGj + r * HPE;
        const float dx = v[0], dy = v[1], dz = v[2];
        if (g < 5) {
            const float nrm = sqrtf(dx * dx + dy * dy + dz * dz);
            const float inv = 1.f / fmaxf(nrm, 1e-12f);
            const float dn[3] = {dx * inv, dy * inv, dz * inv};
            if (g < 4) {
                const float sc = (float)(1 << g);
                float p0[3], p1[3];
#pragma unroll
                for (int c = 0; c < 3; ++c) {
                    const float tv = dn[c] * sc * INV2PI;
                    p0[c] = sinrev(tv);
                    p1[c] = sinrev(tv + 0.25f);
                }
                u32* dst = (u32*)(gr + 16 + 6 * g);  // byte 32+12g, 4-aligned
                dst[0] = pk(p0[0], p0[1]);           // cols 16+6g, +1
                dst[1] = pk(p0[2], p1[0]);           // +2, +3
                dst[2] = pk(p1[1], p1[2]);           // +4, +5
            } else {
                *(u32*)(gr + 40) = pk(dn[0], dn[1]); // cols 40,41
                gr[42] = f2b(dn[2]);
                // cols 15, 43..63 const: prologue-initialized
            }
        }
    }
}

// Producer/consumer wave-specialized fused MLP: 16 waves (4/SIMD), 1 block/CU.
// Final configuration (R14, 504us steady; 636->504 over the session):
//   - R2 2-phase wave-specialized schedule (front: enc+L1+L2; back: L3+L4/ch1/head)
//   - bar_lds: lgkmcnt-only barriers (no vmcnt drain)            [R10, +15us]
//   - constant LDS columns hoisted to prologue                    [R13, +10us]
//   - interleaved enc columns -> vector ds_write, ch1 NKT=3       [R14, +12us]
//   Measured-null/regressions: 2 blocks/CU (spills weights), phase merges/splits,
//   deep preload (barrier drains it), setprio (lockstep), 16x16 layers (bank
//   conflicts 3.2x), cvt_pk pack (RTZ truncation breaks tolerance).
//   A(i): front: enc_preload(i+1); L1(i): sE->sB; enc_compute(i+1)->sE',sG
//         back:  L3(i-1): sC->sD
//   B(i): front: L2(i): sB->sC
//         back:  bw4,5: L4(i-1): sD->sG.feat+density | bw0-3: ch1(i-2): sG->sF
//                | bw6,7: head(i-3): sF->rgb
// Buffers: sE x2 (enc j -> buf j&1), sG x4 (dir j @A(j-1) slot j&3, feat @B(j+1),
//          read @B(j+2), reuse @A(j+3)), sF x2 (ch1 j -> buf j&1, head reads @B(j+3)).
__global__ __launch_bounds__(1024, 4) void ngp_fused(
    const float* __restrict__ pos, const float* __restrict__ dir, const u16* __restrict__ ws,
    const float* __restrict__ b2, const float* __restrict__ b3,
    const float* __restrict__ b4, const float* __restrict__ bc2,
    float* __restrict__ out) {
    __shared__ __align__(16) u16 sE[2][32][HPE];    // encode out (64c), double-buffered
    __shared__ __align__(16) u16 sB[32][HPB];       // L1 out (256c)
    __shared__ __align__(16) u16 sC[32][HPB];       // L2 out (256c)
    __shared__ __align__(16) u16 sD[32][HPB];       // L3 out (256c)
    __shared__ __align__(16) u16 sG[4][32][HPE];    // color in (64c), 4-deep rotation
    __shared__ __align__(16) u16 sF[2][32][HPF];    // ch1 out (128c)
    const int t = threadIdx.x;
    const int lane = t & 63;
    const int w = t >> 6;                        // 16 waves
    const int bw = w - 8;                        // back-wave index (valid w>=8)
    const int ln = lane & 31, kh = lane >> 5;    // 32x32 frag coords
    const int lr = lane & 15, q = lane >> 4;     // 16x16 frag coords

    const u16* WT1  = ws;
    const u16* WT2  = ws + 16384;
    const u16* WT3  = ws + 81920;
    const u16* WT4  = ws + 147456;
    const u16* WTc1 = ws + 151552;
    const u16* WTc2 = ws + 159744;

    // ---- resident weights, unioned across roles (shared physical regs) ----
    short8 wrA[16], wrB[4];
    {
        const u16* pA = (w < 8) ? WT2 + (size_t)(w * 32 + ln) * 256 + kh * 8
                                : WT3 + (size_t)(bw * 32 + ln) * 256 + kh * 8;
#pragma unroll
        for (int kt = 0; kt < 16; ++kt) wrA[kt] = *(const short8*)(pA + kt * 16);
        const u16* pB = (w < 8)  ? WT1 + (size_t)(w * 32 + ln) * 64 + kh * 8
                      : (bw < 4) ? WTc1 + (size_t)(bw * 32 + ln) * 64 + kh * 8
                                 : WT1 + (size_t)ln * 64 + kh * 8;   // dummy (unused)
#pragma unroll
        for (int kt = 0; kt < 4; ++kt) wrB[kt] = *(const short8*)(pB + kt * 16);
    }

    // ---- prologue: init constant LDS columns, then encode tile 0 ----
    {
        // sG: col15 = 0, col43 = 1.0 (bc1 fold), cols 44..63 = 0, all 4 slots.
        if (t < 128) {
            u16* gr = &sG[t >> 5][t & 31][0];
            gr[15] = 0;
            gr[43] = 0x3F80;
#pragma unroll
            for (int c = 44; c < 64; ++c) gr[c] = 0;
        } else if (t < 192) {
            // sE[b][r][63] = 1.0 (b1 fold), both buffers.
            const int t2 = t - 128;
            sE[t2 >> 5][t2 & 31][63] = 0x3F80;
        }
        float pv[3];
        if (t < 512) {
            enc_preload(pos, dir, (long)blockIdx.x * TILES * 32, t, pv);
            enc_compute(pv, t, &sE[0][0][0], &sG[0][0][0]);
        }
        bar_lds();
    }

    for (int i = 0; i <= TILES + 2; ++i) {
        const bool dEnc = (i + 1 < TILES);
        const bool dL1  = (i < TILES);
        const bool dL3  = (i >= 1 && i <= TILES);
        const bool dC1  = (i >= 2 && i <= TILES + 1);
        const bool dHd  = (i >= 3);

        // ========== Phase A: enc_preload(i+1)+L1(i)+enc_compute(i+1) [front] | L3(i-1) [back] ==========
        float pv[3];
        if (dEnc && t < 512)
            enc_preload(pos, dir, ((long)blockIdx.x * TILES + i + 1) * 32, t, pv);
        if (dL1 && w < 8)
            layer32<4, false>(wrB, &sE[i & 1][0][0], HPE, &sB[0][0], HPB, nullptr, w * 32, ln, kh);
        if (dL3 && w >= 8)
            layer32<16, true>(wrA, &sC[0][0], HPB, &sD[0][0], HPB, b3, bw * 32, ln, kh);
        if (dEnc && t < 512)
            enc_compute(pv, t, &sE[(i + 1) & 1][0][0], &sG[(i + 1) & 3][0][0]);
        bar_lds();

        // ========== Phase B: L2(i) [front] | L4(i-1) | ch1(i-2) | head(i-3) [back] ==========
        if (dL1 && w < 8)
            layer32<16, true>(wrA, &sB[0][0], HPB, &sC[0][0], HPB, b2, w * 32, ln, kh);
        if (dL3 && w >= 8 && (bw == 4 || bw == 5)) {
            // L4(i-1): sD -> feat into sG[(i-1)&3] cols 0..14, density -> out
            const long rbM = ((long)blockIdx.x * TILES + i - 1) * 32;
            u16* sGf = &sG[(i - 1) & 3][0][0];
            const int rbase = (bw - 4) * 16;
            f32x4 acc = {0.f, 0.f, 0.f, 0.f};
#pragma unroll
            for (int kt = 0; kt < 8; ++kt) {
                const short8 aF = *(const short8*)&sD[rbase + lr][kt * 32 + q * 8];
                const short8 bF = *(const short8*)(WT4 + lr * 256 + kt * 32 + q * 8);
                acc = __builtin_amdgcn_mfma_f32_16x16x32_bf16(aF, bF, acc, 0, 0, 0);
            }
            const float bi = b4[lr];
#pragma unroll
            for (int r = 0; r < 4; ++r) {
                const float v = acc[r] + bi;
                const int gm = rbase + q * 4 + r;
                if (lr == 0)
                    out[3 * (long)NPTS + rbM + gm] = __expf(v - 1.f);
                else
                    sGf[gm * HPE + lr - 1] = f2b(v);   // feat -> cols 0..14
            }
        }
        if (dC1 && w >= 8 && bw < 4)
            layer32<3, false>(wrB, &sG[(i - 2) & 3][0][0], HPE, &sF[(i - 2) & 1][0][0], HPF,
                              nullptr, bw * 32, ln, kh);
        if (dHd && w >= 8 && (bw == 6 || bw == 7)) {
            // head(i-3): sF[(i-3)&1] -> rgb out
            const long rbH = ((long)blockIdx.x * TILES + i - 3) * 32;
            const int rbase = (bw - 6) * 16;
            f32x4 acc = {0.f, 0.f, 0.f, 0.f};
#pragma unroll
            for (int kt = 0; kt < 4; ++kt) {
                const short8 aF = *(const short8*)&sF[(i - 3) & 1][rbase + lr][kt * 32 + q * 8];
                const short8 bF = *(const short8*)(WTc2 + lr * 128 + kt * 32 + q * 8);
                acc = __builtin_amdgcn_mfma_f32_16x16x32_bf16(aF, bF, acc, 0, 0, 0);
            }
            if (lr < 3) {
                const float bi = bc2[lr];
#pragma unroll
                for (int r = 0; r < 4; ++r) {
                    const float v = acc[r] + bi;
                    const float sg = 1.f / (1.f + __expf(-v));
                    out[(rbH + rbase + q * 4 + r) * 3 + lr] = sg;
                }
            }
        }
        bar_lds();
    }
}

extern "C" void kernel_launch(void* const* d_in, const int* in_sizes, int n_in,
                              void* d_out, int out_size, void* d_ws, size_t ws_size,
                              hipStream_t stream) {
    const float* pos = (const float*)d_in[0];
    const float* dir = (const float*)d_in[1];
    const float* W1  = (const float*)d_in[2];
    const float* b1  = (const float*)d_in[3];
    const float* W2  = (const float*)d_in[4];
    const float* b2  = (const float*)d_in[5];
    const float* W3  = (const float*)d_in[6];
    const float* b3  = (const float*)d_in[7];
    const float* W4  = (const float*)d_in[8];
    const float* b4  = (const float*)d_in[9];
    const float* Wc1 = (const float*)d_in[10];
    const float* bc1 = (const float*)d_in[11];
    const float* Wc2 = (const float*)d_in[12];
    const float* bc2 = (const float*)d_in[13];
    u16* ws   = (u16*)d_ws;
    float* out = (float*)d_out;

    prep_weights<<<633, 256, 0, stream>>>(W1, b1, W2, W3, W4, Wc1, bc1, Wc2, ws);
    ngp_fused<<<NBLK, 1024, 0, stream>>>(pos, dir, ws, b2, b3, b4, bc2, out);
}